// Round 2
// baseline (414.606 us; speedup 1.0000x reference)
//
#include <hip/hip_runtime.h>
#include <math.h>

// SPP mix (max + mean), levels {1,2,4}, input (32,64,64,512) fp32 channels-last.
// Single fused kernel: one block per (b, 4x4 bin) computes max/sum over its
// 16x16 window (input read exactly once, HBM-bound), writes level-4 outputs
// directly, and the last block per batch (device-scope atomicInc protocol)
// aggregates levels 2 and 1 from the 16 bin partials in d_ws.

#define B_ 32
#define HW_ 64
#define C_ 512
#define CVEC 128  // C/4 float4 channel-groups

__device__ __forceinline__ float4 f4max(float4 a, float4 b) {
    return make_float4(fmaxf(a.x, b.x), fmaxf(a.y, b.y),
                       fmaxf(a.z, b.z), fmaxf(a.w, b.w));
}
__device__ __forceinline__ float4 f4add(float4 a, float4 b) {
    return make_float4(a.x + b.x, a.y + b.y, a.z + b.z, a.w + b.w);
}
__device__ __forceinline__ float4 f4mix(float4 m, float4 s, float inv) {
    return make_float4(m.x + s.x * inv, m.y + s.y * inv,
                       m.z + s.z * inv, m.w + s.w * inv);
}

// One block per (b, bin); bin = br*4+bc over the 4x4 grid of 16x16 windows.
// 512 threads = 128 channel-groups x 4 row-quarters (4 rows each).
__global__ __launch_bounds__(512) void spp_fused_kernel(
    const float4* __restrict__ x,
    float4* __restrict__ maxbuf,
    float4* __restrict__ sumbuf,
    unsigned int* counters,          // per-b, stride 64 uints (256 B)
    float4* __restrict__ out)
{
    const int blk = blockIdx.x;      // [0, B_*16)
    const int b   = blk >> 4;
    const int bin = blk & 15;
    const int br  = bin >> 2;
    const int bc  = bin & 3;
    const int tid = threadIdx.x;
    const int cg  = tid & (CVEC - 1);
    const int q   = tid >> 7;        // row-quarter 0..3

    // float4 index of x[b][br*16 + q*4][bc*16][4*cg]
    const int base = ((b * HW_ + br * 16 + q * 4) * HW_ + bc * 16) * CVEC + cg;

    float4 mx = make_float4(-INFINITY, -INFINITY, -INFINITY, -INFINITY);
    float4 sm = make_float4(0.f, 0.f, 0.f, 0.f);

    #pragma unroll 8
    for (int k = 0; k < 64; ++k) {
        const int r = k >> 4;        // row within quarter
        const int j = k & 15;        // col within window
        const float4 v = x[base + (r * HW_ + j) * CVEC];
        mx = f4max(mx, v);
        sm = f4add(sm, v);
    }

    __shared__ float4 smax[3][CVEC];
    __shared__ float4 ssum[3][CVEC];
    __shared__ int lastflag;

    if (q > 0) { smax[q - 1][cg] = mx; ssum[q - 1][cg] = sm; }
    __syncthreads();
    if (q == 0) {
        mx = f4max(f4max(mx, smax[0][cg]), f4max(smax[1][cg], smax[2][cg]));
        sm = f4add(f4add(sm, ssum[0][cg]), f4add(ssum[1][cg], ssum[2][cg]));
        const int o = (b * 16 + bin) * CVEC + cg;
        maxbuf[o] = mx;
        sumbuf[o] = sm;
        // level 4 output: offset 5C floats, element (bc*4+br)*C + c
        out[b * (21 * CVEC) + 5 * CVEC + (bc * 4 + br) * CVEC + cg] =
            f4mix(mx, sm, 1.0f / 256.0f);
        __threadfence();             // make partials device-visible
    }
    __syncthreads();

    if (tid == 0) {
        // Counter starts at 0xAAAAAAAA (poison) or 15 (leftover): both >= 15,
        // so the first arrival wraps to 0 and the 16th arrival returns 14.
        unsigned int ret = atomicInc(&counters[b * 64], 15u);
        lastflag = (ret == 14u) ? 1 : 0;
    }
    __syncthreads();

    if (lastflag && tid < CVEC) {
        __threadfence();             // acquire: see other blocks' partials
        const int pbase = b * 16 * CVEC + cg;
        const int row   = b * (21 * CVEC);
        float4 m1 = make_float4(-INFINITY, -INFINITY, -INFINITY, -INFINITY);
        float4 s1 = make_float4(0.f, 0.f, 0.f, 0.f);
        #pragma unroll
        for (int pr = 0; pr < 2; ++pr) {
            #pragma unroll
            for (int pc = 0; pc < 2; ++pc) {
                float4 mm = make_float4(-INFINITY, -INFINITY, -INFINITY, -INFINITY);
                float4 ss = make_float4(0.f, 0.f, 0.f, 0.f);
                #pragma unroll
                for (int dr = 0; dr < 2; ++dr) {
                    #pragma unroll
                    for (int dc = 0; dc < 2; ++dc) {
                        const int bb = (2 * pr + dr) * 4 + (2 * pc + dc);
                        mm = f4max(mm, maxbuf[pbase + bb * CVEC]);
                        ss = f4add(ss, sumbuf[pbase + bb * CVEC]);
                    }
                }
                // level 2 output: offset C floats, element (pc*2+pr)*C + c
                out[row + CVEC + (pc * 2 + pr) * CVEC + cg] =
                    f4mix(mm, ss, 1.0f / 1024.0f);
                m1 = f4max(m1, mm);
                s1 = f4add(s1, ss);
            }
        }
        // level 1 output: offset 0
        out[row + cg] = f4mix(m1, s1, 1.0f / 4096.0f);
    }
}

extern "C" void kernel_launch(void* const* d_in, const int* in_sizes, int n_in,
                              void* d_out, int out_size, void* d_ws, size_t ws_size,
                              hipStream_t stream) {
    const float4* x = (const float4*)d_in[0];
    float* ws = (float*)d_ws;
    float4* maxbuf = (float4*)ws;                           // 32*16*512 floats = 1 MB
    float4* sumbuf = (float4*)(ws + B_ * 16 * C_);          // 1 MB
    unsigned int* counters = (unsigned int*)(ws + 2 * B_ * 16 * C_);  // 32 x 256 B
    float4* out = (float4*)d_out;

    spp_fused_kernel<<<B_ * 16, 512, 0, stream>>>(x, maxbuf, sumbuf, counters, out);
}

// Round 3
// 369.489 us; speedup vs baseline: 1.1221x; 1.1221x over previous
//
#include <hip/hip_runtime.h>
#include <math.h>

// SPP mix (max + mean), levels {1,2,4}, input (32,64,64,512) fp32 channels-last.
// K1: one block per (b, image-row) streams a contiguous 128 KB slab (copy-probe
//     access pattern) -> per-(b,row,bc) max/sum partials in ws.
// K2: one block per (b, 4x4 bin) folds 16 row-partials -> bin max/sum + level-4 out.
// K3: tiny aggregator for levels 2 and 1 (R1-proven).

#define B_ 32
#define HW_ 64
#define C_ 512
#define CVEC 128  // C/4 float4 channel-groups

__device__ __forceinline__ float4 f4max(float4 a, float4 b) {
    return make_float4(fmaxf(a.x, b.x), fmaxf(a.y, b.y),
                       fmaxf(a.z, b.z), fmaxf(a.w, b.w));
}
__device__ __forceinline__ float4 f4add(float4 a, float4 b) {
    return make_float4(a.x + b.x, a.y + b.y, a.z + b.z, a.w + b.w);
}
__device__ __forceinline__ float4 f4mix(float4 m, float4 s, float inv) {
    return make_float4(m.x + s.x * inv, m.y + s.y * inv,
                       m.z + s.z * inv, m.w + s.w * inv);
}

// K1: block = b*64+i (one image row = 64 px * 512 ch = 8192 float4, contiguous).
// Thread t reads row[k*256 + t], k=0..31: pure sequential streaming.
// For t in [0,256): bc = (k*256+t)>>11 == k>>3 (uniform over the block).
// Channel-group of element (k*256+t) is t&127; threads t and t+128 cover
// disjoint column sets -> combine via LDS.
__global__ __launch_bounds__(256) void spp_rows_kernel(
    const float4* __restrict__ x,
    float4* __restrict__ rmax,
    float4* __restrict__ rsum)
{
    const int blk = blockIdx.x;          // [0, B_*HW_)
    const int t   = threadIdx.x;
    const float4* row = x + (size_t)blk * (HW_ * CVEC);

    float4 m[4], s[4];
    #pragma unroll
    for (int bc = 0; bc < 4; ++bc) {
        m[bc] = make_float4(-INFINITY, -INFINITY, -INFINITY, -INFINITY);
        s[bc] = make_float4(0.f, 0.f, 0.f, 0.f);
        #pragma unroll
        for (int k8 = 0; k8 < 8; ++k8) {
            const float4 v = row[(bc * 8 + k8) * 256 + t];
            m[bc] = f4max(m[bc], v);
            s[bc] = f4add(s[bc], v);
        }
    }

    __shared__ float4 lm[4][CVEC];
    __shared__ float4 ls[4][CVEC];
    if (t >= CVEC) {
        #pragma unroll
        for (int bc = 0; bc < 4; ++bc) { lm[bc][t - CVEC] = m[bc]; ls[bc][t - CVEC] = s[bc]; }
    }
    __syncthreads();
    if (t < CVEC) {
        #pragma unroll
        for (int bc = 0; bc < 4; ++bc) {
            m[bc] = f4max(m[bc], lm[bc][t]);
            s[bc] = f4add(s[bc], ls[bc][t]);
            const int o = (blk * 4 + bc) * CVEC + t;
            rmax[o] = m[bc];
            rsum[o] = s[bc];
        }
    }
}

// K2: block = b*16 + bin (bin = br*4+bc). 256 threads = 128 cg x 2 row-halves.
// Folds 16 row-partials into the bin's max/sum, writes level-4 output.
__global__ __launch_bounds__(256) void spp_bins_kernel(
    const float4* __restrict__ rmax,
    const float4* __restrict__ rsum,
    float4* __restrict__ bmax,
    float4* __restrict__ bsum,
    float4* __restrict__ out)
{
    const int blk = blockIdx.x;          // [0, B_*16)
    const int b   = blk >> 4;
    const int bin = blk & 15;
    const int br  = bin >> 2;
    const int bc  = bin & 3;
    const int t   = threadIdx.x;
    const int cg  = t & (CVEC - 1);
    const int ih  = t >> 7;              // row-half 0/1

    float4 m = make_float4(-INFINITY, -INFINITY, -INFINITY, -INFINITY);
    float4 s = make_float4(0.f, 0.f, 0.f, 0.f);
    #pragma unroll
    for (int r = 0; r < 8; ++r) {
        const int i = br * 16 + ih * 8 + r;
        const int o = ((b * HW_ + i) * 4 + bc) * CVEC + cg;
        m = f4max(m, rmax[o]);
        s = f4add(s, rsum[o]);
    }

    __shared__ float4 lm[CVEC];
    __shared__ float4 ls[CVEC];
    if (ih) { lm[cg] = m; ls[cg] = s; }
    __syncthreads();
    if (!ih) {
        m = f4max(m, lm[cg]);
        s = f4add(s, ls[cg]);
        const int o = (b * 16 + bin) * CVEC + cg;
        bmax[o] = m;
        bsum[o] = s;
        // level 4: offset 5C floats, element (bc*4+br)*C + c
        out[b * (21 * CVEC) + 5 * CVEC + (bc * 4 + br) * CVEC + cg] =
            f4mix(m, s, 1.0f / 256.0f);
    }
}

// K3: per (b, cg): read 16 bin partials, emit levels 2 and 1.
__global__ __launch_bounds__(256) void spp_agg_kernel(
    const float4* __restrict__ bmax,
    const float4* __restrict__ bsum,
    float4* __restrict__ out)
{
    const int idx = blockIdx.x * 256 + threadIdx.x;  // [0, B_*CVEC)
    const int b   = idx >> 7;
    const int cg  = idx & (CVEC - 1);
    const int pbase = b * 16 * CVEC + cg;
    const int row   = b * (21 * CVEC);

    float4 m1 = make_float4(-INFINITY, -INFINITY, -INFINITY, -INFINITY);
    float4 s1 = make_float4(0.f, 0.f, 0.f, 0.f);
    #pragma unroll
    for (int pr = 0; pr < 2; ++pr) {
        #pragma unroll
        for (int pc = 0; pc < 2; ++pc) {
            float4 mm = make_float4(-INFINITY, -INFINITY, -INFINITY, -INFINITY);
            float4 ss = make_float4(0.f, 0.f, 0.f, 0.f);
            #pragma unroll
            for (int dr = 0; dr < 2; ++dr) {
                #pragma unroll
                for (int dc = 0; dc < 2; ++dc) {
                    const int bb = (2 * pr + dr) * 4 + (2 * pc + dc);
                    mm = f4max(mm, bmax[pbase + bb * CVEC]);
                    ss = f4add(ss, bsum[pbase + bb * CVEC]);
                }
            }
            // level 2: offset C floats, element (pc*2+pr)*C + c
            out[row + CVEC + (pc * 2 + pr) * CVEC + cg] =
                f4mix(mm, ss, 1.0f / 1024.0f);
            m1 = f4max(m1, mm);
            s1 = f4add(s1, ss);
        }
    }
    out[row + cg] = f4mix(m1, s1, 1.0f / 4096.0f);
}

extern "C" void kernel_launch(void* const* d_in, const int* in_sizes, int n_in,
                              void* d_out, int out_size, void* d_ws, size_t ws_size,
                              hipStream_t stream) {
    const float4* x = (const float4*)d_in[0];
    float* ws = (float*)d_ws;
    // rmax/rsum: 32*64*4*512 floats = 4M floats = 16 MB each
    float4* rmax = (float4*)ws;
    float4* rsum = (float4*)(ws + (size_t)B_ * HW_ * 4 * C_);
    // bmax/bsum: 32*16*512 floats = 1 MB each
    float4* bmax = (float4*)(ws + (size_t)2 * B_ * HW_ * 4 * C_);
    float4* bsum = (float4*)(ws + (size_t)2 * B_ * HW_ * 4 * C_ + B_ * 16 * C_);
    float4* out = (float4*)d_out;

    spp_rows_kernel<<<B_ * HW_, 256, 0, stream>>>(x, rmax, rsum);
    spp_bins_kernel<<<B_ * 16, 256, 0, stream>>>(rmax, rsum, bmax, bsum, out);
    spp_agg_kernel<<<(B_ * CVEC) / 256, 256, 0, stream>>>(bmax, bsum, out);
}

// Round 4
// 361.697 us; speedup vs baseline: 1.1463x; 1.0215x over previous
//
#include <hip/hip_runtime.h>
#include <math.h>

// SPP mix (max + mean), levels {1,2,4}, input (32,64,64,512) fp32 channels-last.
// K1: one block per (b, row-pair): streams a contiguous 256 KB slab (pure
//     sequential, copy-probe pattern), folds the 2 rows -> per-(pair,bc)
//     max/sum partials in ws (16 MB total).
// K2: one block per batch (32 blocks, 512 threads): folds 8 pair-partials per
//     bin -> 16 bins in LDS -> level-4 outputs, then levels 2 and 1 in-block.

#define B_ 32
#define HW_ 64
#define C_ 512
#define CVEC 128  // C/4 float4 channel-groups

__device__ __forceinline__ float4 f4max(float4 a, float4 b) {
    return make_float4(fmaxf(a.x, b.x), fmaxf(a.y, b.y),
                       fmaxf(a.z, b.z), fmaxf(a.w, b.w));
}
__device__ __forceinline__ float4 f4add(float4 a, float4 b) {
    return make_float4(a.x + b.x, a.y + b.y, a.z + b.z, a.w + b.w);
}
__device__ __forceinline__ float4 f4mix(float4 m, float4 s, float inv) {
    return make_float4(m.x + s.x * inv, m.y + s.y * inv,
                       m.z + s.z * inv, m.w + s.w * inv);
}

// K1: block = b*32 + pair; rows 2*pair, 2*pair+1 (contiguous 16384 float4).
// Thread t reads slab[(bc*8+k8)*256 + t] and slab[... + 8192]: fully
// sequential 256 KB per block. bc = column-bin, uniform per (bc,k8) step.
// cg of element is t&127; threads t and t+128 cover disjoint columns -> LDS fold.
__global__ __launch_bounds__(256) void spp_pairs_kernel(
    const float4* __restrict__ x,
    float4* __restrict__ pmax,
    float4* __restrict__ psum)
{
    const int blk = blockIdx.x;          // [0, B_*32)
    const int t   = threadIdx.x;
    const float4* slab = x + (size_t)blk * (2 * HW_ * CVEC);

    float4 m[4], s[4];
    #pragma unroll
    for (int bc = 0; bc < 4; ++bc) {
        m[bc] = make_float4(-INFINITY, -INFINITY, -INFINITY, -INFINITY);
        s[bc] = make_float4(0.f, 0.f, 0.f, 0.f);
        #pragma unroll
        for (int k8 = 0; k8 < 8; ++k8) {
            const int o = (bc * 8 + k8) * 256 + t;
            const float4 v0 = slab[o];
            const float4 v1 = slab[o + HW_ * CVEC];
            m[bc] = f4max(m[bc], f4max(v0, v1));
            s[bc] = f4add(s[bc], f4add(v0, v1));
        }
    }

    __shared__ float4 lm[4][CVEC];
    __shared__ float4 ls[4][CVEC];
    if (t >= CVEC) {
        #pragma unroll
        for (int bc = 0; bc < 4; ++bc) { lm[bc][t - CVEC] = m[bc]; ls[bc][t - CVEC] = s[bc]; }
    }
    __syncthreads();
    if (t < CVEC) {
        #pragma unroll
        for (int bc = 0; bc < 4; ++bc) {
            m[bc] = f4max(m[bc], lm[bc][t]);
            s[bc] = f4add(s[bc], ls[bc][t]);
            const int o = (blk * 4 + bc) * CVEC + t;
            pmax[o] = m[bc];
            psum[o] = s[bc];
        }
    }
}

// K2: one block per batch b; 512 threads = 4 bin-rows (br) x 128 cg.
// Thread (br,cg): for each bc, fold 8 pair-partials -> bin (br,bc); write
// level-4 output and park bin in LDS. Then first 128 threads do levels 2,1.
__global__ __launch_bounds__(512) void spp_agg_kernel(
    const float4* __restrict__ pmax,
    const float4* __restrict__ psum,
    float4* __restrict__ out)
{
    const int b  = blockIdx.x;           // [0, B_)
    const int t  = threadIdx.x;
    const int br = t >> 7;               // bin row 0..3
    const int cg = t & (CVEC - 1);
    const int row = b * (21 * CVEC);

    __shared__ float4 lm[16][CVEC];      // 32 KB
    __shared__ float4 ls[16][CVEC];      // 32 KB

    #pragma unroll
    for (int bc = 0; bc < 4; ++bc) {
        float4 m = make_float4(-INFINITY, -INFINITY, -INFINITY, -INFINITY);
        float4 s = make_float4(0.f, 0.f, 0.f, 0.f);
        #pragma unroll
        for (int p8 = 0; p8 < 8; ++p8) {
            const int pair = br * 8 + p8;            // rows 16*br .. 16*br+15
            const int o = ((b * 32 + pair) * 4 + bc) * CVEC + cg;
            m = f4max(m, pmax[o]);
            s = f4add(s, psum[o]);
        }
        lm[br * 4 + bc][cg] = m;
        ls[br * 4 + bc][cg] = s;
        // level 4: offset 5C floats, element (bc*4+br)*C + c
        out[row + 5 * CVEC + (bc * 4 + br) * CVEC + cg] =
            f4mix(m, s, 1.0f / 256.0f);
    }
    __syncthreads();

    if (t < CVEC) {
        float4 m1 = make_float4(-INFINITY, -INFINITY, -INFINITY, -INFINITY);
        float4 s1 = make_float4(0.f, 0.f, 0.f, 0.f);
        #pragma unroll
        for (int pr = 0; pr < 2; ++pr) {
            #pragma unroll
            for (int pc = 0; pc < 2; ++pc) {
                float4 mm = make_float4(-INFINITY, -INFINITY, -INFINITY, -INFINITY);
                float4 ss = make_float4(0.f, 0.f, 0.f, 0.f);
                #pragma unroll
                for (int dr = 0; dr < 2; ++dr) {
                    #pragma unroll
                    for (int dc = 0; dc < 2; ++dc) {
                        const int bin = (2 * pr + dr) * 4 + (2 * pc + dc);
                        mm = f4max(mm, lm[bin][cg]);
                        ss = f4add(ss, ls[bin][cg]);
                    }
                }
                // level 2: offset C floats, element (pc*2+pr)*C + c
                out[row + CVEC + (pc * 2 + pr) * CVEC + cg] =
                    f4mix(mm, ss, 1.0f / 1024.0f);
                m1 = f4max(m1, mm);
                s1 = f4add(s1, ss);
            }
        }
        out[row + cg] = f4mix(m1, s1, 1.0f / 4096.0f);
    }
}

extern "C" void kernel_launch(void* const* d_in, const int* in_sizes, int n_in,
                              void* d_out, int out_size, void* d_ws, size_t ws_size,
                              hipStream_t stream) {
    const float4* x = (const float4*)d_in[0];
    float* ws = (float*)d_ws;
    // pmax/psum: 32*32 pairs * 4 bc * 512 ch floats = 2M floats = 8 MB each
    float4* pmax = (float4*)ws;
    float4* psum = (float4*)(ws + (size_t)B_ * 32 * 4 * C_);
    float4* out = (float4*)d_out;

    spp_pairs_kernel<<<B_ * 32, 256, 0, stream>>>(x, pmax, psum);
    spp_agg_kernel<<<B_, 512, 0, stream>>>(pmax, psum, out);
}